// Round 4
// baseline (662.844 us; speedup 1.0000x reference)
//
#include <hip/hip_runtime.h>
#include <hip/hip_bf16.h>

typedef _Float16 f16;
typedef f16 f16x8 __attribute__((ext_vector_type(8)));
typedef f16 f16x4 __attribute__((ext_vector_type(4)));
typedef float f32x4 __attribute__((ext_vector_type(4)));

static constexpr int NDATA = 50000;
static constexpr int DF    = 3072;
static constexpr int BP    = 256;
static constexpr int NLD1  = 50048;   // written W cols (782*64)
static constexpr int NLD2  = 51200;   // W row stride (800*64)
static constexpr int NGRP  = 782;     // k_qk blocks / softmax groups
static constexpr int NDT2  = 48;      // d-tiles of 64 in k_pv

// workspace offsets (bytes)
static constexpr size_t OFF_W  = 0;            // W : 256*51200*2 = 26214400
static constexpr size_t OFF_XH = 26214400;     // xh: 256*3072*2  = 1572864
static constexpr size_t OFF_MP = 27787264;     // Mp: 782*256*4   = 800768
static constexpr size_t OFF_LP = 28588032;     // Lp: 782*256*4   = 800768
static constexpr size_t OFF_M  = 29388800;     // M : 256*4 (+pad)
static constexpr size_t OFF_L  = 29389824;     // L : 256*4 (+pad)
static constexpr size_t OFF_P  = 29390848;     // P : nch * 3145728
static constexpr size_t SLAB   = (size_t)BP * DF * 4;   // 3145728

// ---------------- K1: x -> fp16 ----------------
__global__ void k_prep_x(const float* __restrict__ x, f16* __restrict__ xh) {
  int i = blockIdx.x * 256 + threadIdx.x;          // float4 index, 196608 total
  f32x4 v = ((const f32x4*)x)[i];
  f16x4 h;
  h[0] = (f16)v[0]; h[1] = (f16)v[1]; h[2] = (f16)v[2]; h[3] = (f16)v[3];
  ((f16x4*)xh)[i] = h;
}

// ---------------- K2: W'[b][n] = exp(S - m_blk), Mp/Lp per block ----------------
// 512 thr = 8 waves (4 n-groups x 2 b-halves), tile 64n x 256b, K-step 32.
// S[n][b] = (2*d.x - |d|^2)/(2 sigma^2) computed via MFMA, never materialized:
// block-local softmax partials + direct fp16 W' store (LDS transpose).
static constexpr int QPAD = 40;
static constexpr int TP   = 72;   // trans row pad (f16)
__global__ __launch_bounds__(512) void k_qk(const float* __restrict__ data,
                                            const f16* __restrict__ xh,
                                            const float* __restrict__ sigma,
                                            f16* __restrict__ W,
                                            float* __restrict__ Mp,
                                            float* __restrict__ Lp) {
  __shared__ char smem[51456];
  f16 (*As)[64 * QPAD]  = (f16(*)[64 * QPAD])smem;              // 2 x 5120 B
  f16 (*Bs)[256 * QPAD] = (f16(*)[256 * QPAD])(smem + 10240);   // 2 x 20480 B
  float* dn_s = (float*)(smem + 51200);                          // 256 B
  // post-loop aliases (over As / Bs)
  float* m4   = (float*)smem;                                    // [4][256]
  float* l4   = (float*)(smem + 4096);                           // [4][256]
  float* m_s  = (float*)(smem + 8192);                           // [256]
  f16*  trans = (f16*)(smem + 10240);                            // [256][TP] 36864 B

  const int tid = threadIdx.x;
  const int wid = tid >> 6, lane = tid & 63;
  const int l15 = lane & 15, kg = lane >> 4;
  const int wr = wid >> 1, wb = wid & 1;
  const int n0 = blockIdx.x * 64;

  // A staging: row = tid>>3, 4 floats at (tid&7)*4
  const int arow = tid >> 3;
  const int ak4  = (tid & 7) * 4;
  const int ar_g = n0 + arow;
  const int ar_c = ar_g < NDATA ? ar_g : NDATA - 1;
  const float* ap = data + (size_t)ar_c * DF + ak4;

  // B staging: rows tid>>2 and +128, 8 f16 at (tid&3)*8
  const int brow = tid >> 2;
  const int bk8  = (tid & 3) * 8;
  const f16* bp0 = xh + (size_t)brow * DF + bk8;
  const f16* bp1 = xh + (size_t)(brow + 128) * DF + bk8;

  f32x4 acc[8] = {};
  float sq = 0.f;
  f32x4 gaA, gaB;
  f16x8 gb0A, gb1A, gb0B, gb1B;

  auto gload = [&](int k0, f32x4& ga, f16x8& g0, f16x8& g1) {
    ga = *(const f32x4*)(ap + k0);
    g0 = *(const f16x8*)(bp0 + k0);
    g1 = *(const f16x8*)(bp1 + k0);
  };
  auto swrite = [&](int buf, f32x4& ga, f16x8& g0, f16x8& g1) {
    f16x4 h;
#pragma unroll
    for (int j = 0; j < 4; ++j) { h[j] = (f16)ga[j]; sq = fmaf(ga[j], ga[j], sq); }
    *(f16x4*)(&As[buf][arow * QPAD + ak4]) = h;
    *(f16x8*)(&Bs[buf][brow * QPAD + bk8]) = g0;
    *(f16x8*)(&Bs[buf][(brow + 128) * QPAD + bk8]) = g1;
  };
  auto compute = [&](int buf) {
    f16x8 af = *(const f16x8*)(&As[buf][(wr * 16 + l15) * QPAD + kg * 8]);
#pragma unroll
    for (int c = 0; c < 8; ++c) {
      f16x8 bf = *(const f16x8*)(&Bs[buf][(wb * 128 + c * 16 + l15) * QPAD + kg * 8]);
      acc[c] = __builtin_amdgcn_mfma_f32_16x16x32_f16(af, bf, acc[c], 0, 0, 0);
    }
  };

  gload(0, gaA, gb0A, gb1A);
  swrite(0, gaA, gb0A, gb1A);
  gload(32, gaB, gb0B, gb1B);
  __syncthreads();

  for (int ks = 0; ks < 96; ks += 2) {
    if (ks + 2 < 96) gload((ks + 2) * 32, gaA, gb0A, gb1A);
    compute(0);
    swrite(1, gaB, gb0B, gb1B);
    __syncthreads();
    if (ks + 3 < 96) gload((ks + 3) * 32, gaB, gb0B, gb1B);
    compute(1);
    if (ks + 2 < 96) swrite(0, gaA, gb0A, gb1A);
    __syncthreads();
  }

  // |d|^2 reduce across the 8 k-chunk threads of each row
  sq += __shfl_xor(sq, 1);
  sq += __shfl_xor(sq, 2);
  sq += __shfl_xor(sq, 4);
  if ((lane & 7) == 0) dn_s[wid * 8 + (lane >> 3)] = sq;
  __syncthreads();

  const float sg  = sigma[0];
  const float inv = 0.5f / (sg * sg);
  float dn[4];
  bool ok[4];
#pragma unroll
  for (int r = 0; r < 4; ++r) {
    const int trow = wr * 16 + kg * 4 + r;       // C/D: row=(l>>4)*4+reg
    dn[r] = dn_s[trow];
    ok[r] = (n0 + trow) < NDATA;
  }

  // pass 1: block-local column max
  float pm[8];
#pragma unroll
  for (int c = 0; c < 8; ++c) pm[c] = -1e30f;
#pragma unroll
  for (int r = 0; r < 4; ++r)
#pragma unroll
    for (int c = 0; c < 8; ++c) {
      float v = ok[r] ? (2.f * acc[c][r] - dn[r]) * inv : -1e30f;
      pm[c] = fmaxf(pm[c], v);
    }
#pragma unroll
  for (int c = 0; c < 8; ++c) {
    pm[c] = fmaxf(pm[c], __shfl_xor(pm[c], 16));
    pm[c] = fmaxf(pm[c], __shfl_xor(pm[c], 32));
  }
  if (kg == 0) {
#pragma unroll
    for (int c = 0; c < 8; ++c) m4[wr * 256 + wb * 128 + c * 16 + l15] = pm[c];
  }
  __syncthreads();
  if (tid < 256)
    m_s[tid] = fmaxf(fmaxf(m4[tid], m4[256 + tid]), fmaxf(m4[512 + tid], m4[768 + tid]));
  __syncthreads();

  // pass 2: w = exp(v - m_blk), accumulate l, store transposed fp16
  float mcol[8];
#pragma unroll
  for (int c = 0; c < 8; ++c) mcol[c] = m_s[wb * 128 + c * 16 + l15];
  float pl[8] = {};
#pragma unroll
  for (int r = 0; r < 4; ++r) {
    const int trow = wr * 16 + kg * 4 + r;
#pragma unroll
    for (int c = 0; c < 8; ++c) {
      float v = (2.f * acc[c][r] - dn[r]) * inv;
      float w = ok[r] ? __expf(v - mcol[c]) : 0.f;
      pl[c] += w;
      trans[(wb * 128 + c * 16 + l15) * TP + trow] = (f16)w;
    }
  }
#pragma unroll
  for (int c = 0; c < 8; ++c) {
    pl[c] += __shfl_xor(pl[c], 16);
    pl[c] += __shfl_xor(pl[c], 32);
  }
  if (kg == 0) {
#pragma unroll
    for (int c = 0; c < 8; ++c) l4[wr * 256 + wb * 128 + c * 16 + l15] = pl[c];
  }
  __syncthreads();
  if (tid < 256) {
    Mp[blockIdx.x * 256 + tid] = m_s[tid];
    Lp[blockIdx.x * 256 + tid] = l4[tid] + l4[256 + tid] + l4[512 + tid] + l4[768 + tid];
  }
  // transpose readout -> W' (64 contiguous f16 per column)
  {
    const int col = tid >> 1, q = tid & 1;
    const f16* src = trans + col * TP + q * 32;
    f16* dst = W + (size_t)col * NLD2 + n0 + q * 32;
#pragma unroll
    for (int j = 0; j < 4; ++j)
      *(f16x8*)(dst + j * 8) = *(const f16x8*)(src + j * 8);
  }
}

// ---------------- K3: combine partials -> M[b], L[b] ----------------
__global__ void k_comb(const float* __restrict__ Mp, const float* __restrict__ Lp,
                       float* __restrict__ M, float* __restrict__ L, int ngrp) {
  __shared__ float ms[4][256], ls[4][256];
  const int tid = threadIdx.x;
  const int q = tid >> 8, b = tid & 255;
  float m = -1e38f, l = 0.f;
  for (int g = q; g < ngrp; g += 4) {
    float m2 = Mp[g * 256 + b], l2 = Lp[g * 256 + b];
    if (m2 > m) { l = l * __expf(m - m2) + l2; m = m2; }
    else        { l += l2 * __expf(m2 - m); }
  }
  ms[q][b] = m; ls[q][b] = l;
  __syncthreads();
  if (q == 0) {
#pragma unroll
    for (int j = 1; j < 4; ++j) {
      float m2 = ms[j][b], l2 = ls[j][b];
      if (m2 > m) { l = l * __expf(m - m2) + l2; m = m2; }
      else        { l += l2 * __expf(m2 - m); }
    }
    M[b] = m; L[b] = l;
  }
}

// ---------------- K4: W *= exp(Mp - M) in place; zero padded cols ----------------
__global__ void k_wscale(f16* __restrict__ W, const float* __restrict__ Mp,
                         const float* __restrict__ M) {
  const int g = blockIdx.x;
  const int n0 = g * 64;
  const int tid = threadIdx.x;
  const int coff = tid >> 3, sub = tid & 7;
  if (g >= NGRP) {           // n >= NLD1: zero (poison cleanup)
#pragma unroll
    for (int it = 0; it < 8; ++it) {
      int col = coff + it * 32;
      f16x8 z = {};
      *(f16x8*)(W + (size_t)col * NLD2 + n0 + sub * 8) = z;
    }
    return;
  }
#pragma unroll
  for (int it = 0; it < 8; ++it) {
    int col = coff + it * 32;
    float f = __expf(Mp[g * 256 + col] - M[col]);
    f16* p = W + (size_t)col * NLD2 + n0 + sub * 8;
    f16x8 w = *(const f16x8*)p;
#pragma unroll
    for (int j = 0; j < 8; ++j) w[j] = (f16)((float)w[j] * f);
    *(f16x8*)p = w;
  }
}

// ---------------- K5: eps partials = W @ data (split-K over n) ----------------
// 512 thr (8 waves), tile 256b x 64d (wave: 32b x 64d), K-step 32 n.
// acc[2][4] keeps VGPR low -> 2 blocks/CU without forcing. 2-deep data, 1-deep W prefetch.
__global__ __launch_bounds__(512) void k_pv(const float* __restrict__ data,
                                            const f16* __restrict__ W,
                                            float* __restrict__ part,
                                            int chn, int per8) {
  __shared__ f16 T[2][64 * 40];   // [d][n(32)+pad]
  const int tid = threadIdx.x;
  const int wid = tid >> 6, lane = tid & 63;
  const int l15 = lane & 15, kg = lane >> 4;
  const int bid = blockIdx.x;
  const int swz = (bid & 7) * per8 + (bid >> 3);   // XCD-chunked (grid % 8 == 0)
  const int chunk = swz / NDT2;
  const int dt = swz % NDT2;
  const int d0 = dt * 64;
  const int nstart = chunk * chn;
  const int kst = chn >> 5;
  const int nl = tid >> 4, dl = (tid & 15) * 4;    // staging: 32 n-rows x 16 thr

  f32x4 acc[2][4] = {};

  const f16* wp0 = W + (size_t)(wid * 32 + l15) * NLD2 + nstart + kg * 8;
  const f16* wp1 = W + (size_t)(wid * 32 + 16 + l15) * NLD2 + nstart + kg * 8;

  f32x4 gA, gB;
  f16x8 w0c, w1c, w0n, w1n;

  auto gload = [&](int ks, f32x4& g) {
    int row = nstart + ks * 32 + nl;
    int rc = row < NDATA ? row : NDATA - 1;        // tail rows have W==0
    g = *(const f32x4*)(data + (size_t)rc * DF + d0 + dl);
  };
  auto wload = [&](int ks, f16x8& w0, f16x8& w1) {
    w0 = *(const f16x8*)(wp0 + ks * 32);
    w1 = *(const f16x8*)(wp1 + ks * 32);
  };
  auto twrite = [&](int buf, f32x4& g) {
#pragma unroll
    for (int j = 0; j < 4; ++j) {
      int d = dl + j;
      int pn = nl ^ (((d >> 3) & 3) << 3);         // bank swizzle
      T[buf][d * 40 + pn] = (f16)g[j];
    }
  };
  auto compute = [&](int buf, f16x8& a0, f16x8& a1) {
#pragma unroll
    for (int c = 0; c < 4; ++c) {
      int d = c * 16 + l15;
      int pb = (kg * 8) ^ (((d >> 3) & 3) << 3);
      f16x8 bf = *(const f16x8*)(&T[buf][d * 40 + pb]);
      acc[0][c] = __builtin_amdgcn_mfma_f32_16x16x32_f16(a0, bf, acc[0][c], 0, 0, 0);
      acc[1][c] = __builtin_amdgcn_mfma_f32_16x16x32_f16(a1, bf, acc[1][c], 0, 0, 0);
    }
  };

  gload(0, gA);
  twrite(0, gA);
  wload(0, w0c, w1c);
  gload(1, gB);
  __syncthreads();

  for (int ks = 0; ks < kst; ks += 2) {
    if (ks + 2 < kst) gload(ks + 2, gA);           // data 2 ahead
    wload(ks + 1, w0n, w1n);                       // W 1 ahead (L2-resident)
    compute(0, w0c, w1c);
    twrite(1, gB);
    __syncthreads();
    if (ks + 3 < kst) gload(ks + 3, gB);
    if (ks + 2 < kst) wload(ks + 2, w0c, w1c);
    compute(1, w0n, w1n);
    if (ks + 2 < kst) twrite(0, gA);
    __syncthreads();
  }

  float* pp = part + (size_t)chunk * (BP * DF);
#pragma unroll
  for (int i = 0; i < 2; ++i)
#pragma unroll
    for (int c = 0; c < 4; ++c)
#pragma unroll
      for (int r = 0; r < 4; ++r) {
        int b = wid * 32 + i * 16 + kg * 4 + r;
        int d = d0 + c * 16 + l15;
        pp[(size_t)b * DF + d] = acc[i][c][r];
      }
}

// ---------------- K6: out = (x - (sum partials)/L) / sigma ----------------
__global__ void k_final(const float* __restrict__ x, const float* __restrict__ sigma,
                        const float* __restrict__ part, const float* __restrict__ L,
                        float* __restrict__ out, int nch) {
  int i = blockIdx.x * 256 + threadIdx.x;   // float4 index
  int b = (i * 4) / DF;
  f32x4 s = {};
  for (int c = 0; c < nch; ++c) s += ((const f32x4*)(part + (size_t)c * BP * DF))[i];
  f32x4 xv = ((const f32x4*)x)[i];
  float invL = 1.f / L[b];
  float sg = sigma[0];
  float invsg = 1.f / sg;
  f32x4 r;
#pragma unroll
  for (int j = 0; j < 4; ++j) r[j] = (xv[j] - s[j] * invL) * invsg;
  ((f32x4*)out)[i] = r;
}

extern "C" void kernel_launch(void* const* d_in, const int* in_sizes, int n_in,
                              void* d_out, int out_size, void* d_ws, size_t ws_size,
                              hipStream_t stream) {
  const float* x     = (const float*)d_in[0];
  const float* sigma = (const float*)d_in[1];
  const float* data  = (const float*)d_in[2];
  float* out = (float*)d_out;
  char* ws = (char*)d_ws;

  f16*   W  = (f16*)(ws + OFF_W);
  f16*   xh = (f16*)(ws + OFF_XH);
  float* Mp = (float*)(ws + OFF_MP);
  float* Lp = (float*)(ws + OFF_LP);
  float* M  = (float*)(ws + OFF_M);
  float* L  = (float*)(ws + OFF_L);
  float* P  = (float*)(ws + OFF_P);

  // split-K width chosen by available workspace
  int nch = 24, chn = 2112;
  if (ws_size < OFF_P + 24 * SLAB) { nch = 16; chn = 3200; }
  if (ws_size < OFF_P + 16 * SLAB) { nch = 8;  chn = 6400; }
  const int grid_pv = NDT2 * nch;
  const int per8 = grid_pv / 8;

  k_prep_x<<<768, 256, 0, stream>>>(x, xh);
  k_qk<<<NGRP, 512, 0, stream>>>(data, xh, sigma, W, Mp, Lp);
  k_comb<<<1, 1024, 0, stream>>>(Mp, Lp, M, L, NGRP);
  k_wscale<<<NLD2 / 64, 256, 0, stream>>>(W, Mp, M);
  k_pv<<<grid_pv, 512, 0, stream>>>(data, W, P, chn, per8);
  k_final<<<768, 256, 0, stream>>>(x, sigma, P, L, out, nch);
}

// Round 5
// 522.330 us; speedup vs baseline: 1.2690x; 1.2690x over previous
//
#include <hip/hip_runtime.h>

typedef _Float16 f16;
typedef f16 f16x8 __attribute__((ext_vector_type(8)));
typedef float f32x4 __attribute__((ext_vector_type(4)));

static constexpr int NDATA = 50000;
static constexpr int DF    = 3072;
static constexpr int BP    = 256;
static constexpr int NW    = 50688;   // W row stride / padded N (396*128)
static constexpr int NGRPQ = 396;     // k_qk blocks = softmax groups (128 n each)
static constexpr int NDT2  = 48;      // d-tiles of 64 in k_pv

// workspace offsets (bytes)
static constexpr size_t OFF_W  = 0;            // W : 256*50688*2 = 25952256
static constexpr size_t OFF_XH = 25952256;     // xh: 1572864
static constexpr size_t OFF_MP = 27525120;     // Mp: 396*256*4 = 405504
static constexpr size_t OFF_LP = 27930624;     // Lp: 405504
static constexpr size_t OFF_M  = 28336128;     // M : 1024
static constexpr size_t OFF_L  = 28337152;     // L : 1024
static constexpr size_t OFF_P  = 28338176;     // P : nch * 3145728
static constexpr size_t SLAB   = (size_t)BP * DF * 4;

// lgkm-only barrier: LDS ordered, global loads stay IN FLIGHT (no vmcnt drain)
__device__ __forceinline__ void barrier_lgkm() {
  __builtin_amdgcn_sched_barrier(0);
  asm volatile("s_waitcnt lgkmcnt(0)" ::: "memory");
  __builtin_amdgcn_s_barrier();
  __builtin_amdgcn_sched_barrier(0);
}

// ---------------- K1: x -> fp16 ----------------
__global__ void k_prep_x(const float* __restrict__ x, f16* __restrict__ xh) {
  int i = blockIdx.x * 256 + threadIdx.x;
  f32x4 v = ((const f32x4*)x)[i];
  f16 h0 = (f16)v[0], h1 = (f16)v[1], h2 = (f16)v[2], h3 = (f16)v[3];
  f16x8 dummy;
  short4* o = (short4*)xh;
  union { f16 f[4]; short4 s; } u;
  u.f[0] = h0; u.f[1] = h1; u.f[2] = h2; u.f[3] = h3;
  o[i] = u.s;
  (void)dummy;
}

// ---------------- K2: S-tile via MFMA -> block softmax partials + W' ----------------
// tile 128n x 256b, 8 waves (wave 32n x 128b, acc[2][8]), K-step 32.
// 2-deep A (data HBM) / 1-deep B (xh L2) register prefetch; 1 lgkm-barrier per step.
__global__ __launch_bounds__(512, 4) void k_qk(const float* __restrict__ data,
                                               const f16* __restrict__ xh,
                                               const float* __restrict__ sigma,
                                               f16* __restrict__ W,
                                               float* __restrict__ Mp,
                                               float* __restrict__ Lp) {
  __shared__ char smem[61952];
  f16 (*As)[5120]  = (f16(*)[5120])smem;              // 2 x 10240 B : [128][40]
  f16 (*Bs)[10240] = (f16(*)[10240])(smem + 20480);   // 2 x 20480 B : [256][40]
  float* dn_s = (float*)(smem + 61440);               // [128]
  float* m4   = (float*)smem;                         // alias: [4][256]
  float* l4   = (float*)(smem + 4096);                // alias: [4][256]
  float* m_s  = (float*)(smem + 8192);                // alias: [256]
  f16*  trans = (f16*)(smem + 20480);                 // alias: [256][72]

  const int tid = threadIdx.x;
  const int wid = tid >> 6, lane = tid & 63;
  const int l15 = lane & 15, kg = lane >> 4;
  const int wr = wid >> 1, wb = wid & 1;
  const int n0 = blockIdx.x * 128;

  // A staging: row = tid>>2 (128 rows), 8 floats at (tid&3)*8
  const int arow = tid >> 2, ak = (tid & 3) * 8;
  const int ar_g = n0 + arow;
  const float* ap = data + (size_t)(ar_g < NDATA ? ar_g : NDATA - 1) * DF + ak;
  // B staging: row = tid>>1 (256 rows), 16 f16 at (tid&1)*16
  const int brow = tid >> 1, bk = (tid & 1) * 16;
  const f16* bp = xh + (size_t)brow * DF + bk;

  f32x4 acc[2][8] = {};
  float sq = 0.f;
  f32x4 a0A, a1A, a0B, a1B;     // two A prefetch sets
  f16x8 rb0, rb1;               // one B prefetch set

  auto gloadA = [&](int k0, f32x4& a0, f32x4& a1) {
    a0 = *(const f32x4*)(ap + k0);
    a1 = *(const f32x4*)(ap + k0 + 4);
  };
  auto gloadB = [&](int k0) {
    rb0 = *(const f16x8*)(bp + k0);
    rb1 = *(const f16x8*)(bp + k0 + 8);
  };
  auto swriteA = [&](int buf, f32x4& a0, f32x4& a1) {
    f16x8 h;
#pragma unroll
    for (int j = 0; j < 4; ++j) {
      h[j] = (f16)a0[j];     sq = fmaf(a0[j], a0[j], sq);
      h[4 + j] = (f16)a1[j]; sq = fmaf(a1[j], a1[j], sq);
    }
    *(f16x8*)(&As[buf][arow * 40 + ak]) = h;
  };
  auto swriteB = [&](int buf) {
    *(f16x8*)(&Bs[buf][brow * 40 + bk]) = rb0;
    *(f16x8*)(&Bs[buf][brow * 40 + bk + 8]) = rb1;
  };
  auto compute = [&](int buf) {
    f16x8 af0 = *(const f16x8*)(&As[buf][(wr * 32 + l15) * 40 + kg * 8]);
    f16x8 af1 = *(const f16x8*)(&As[buf][(wr * 32 + 16 + l15) * 40 + kg * 8]);
#pragma unroll
    for (int c = 0; c < 8; ++c) {
      f16x8 bf = *(const f16x8*)(&Bs[buf][(wb * 128 + c * 16 + l15) * 40 + kg * 8]);
      acc[0][c] = __builtin_amdgcn_mfma_f32_16x16x32_f16(af0, bf, acc[0][c], 0, 0, 0);
      acc[1][c] = __builtin_amdgcn_mfma_f32_16x16x32_f16(af1, bf, acc[1][c], 0, 0, 0);
    }
  };

  gloadA(0, a0A, a1A);
  gloadB(0);
  swriteA(0, a0A, a1A);
  swriteB(0);
  gloadA(32, a0B, a1B);
  barrier_lgkm();

  for (int ks = 0; ks < 96; ks += 2) {
    // step ks (buf 0)
    if (ks + 2 < 96) gloadA((ks + 2) * 32, a0A, a1A);
    gloadB((ks + 1) * 32);                 // ks+1 <= 95 always
    compute(0);
    swriteA(1, a0B, a1B);                  // step ks+1 data
    swriteB(1);
    barrier_lgkm();
    // step ks+1 (buf 1)
    if (ks + 3 < 96) { gloadA((ks + 3) * 32, a0B, a1B); }
    if (ks + 2 < 96) { gloadB((ks + 2) * 32); }
    compute(1);
    if (ks + 2 < 96) { swriteA(0, a0A, a1A); swriteB(0); }
    barrier_lgkm();
  }

  // |d|^2: reduce over 4 k-quarter threads of each row
  sq += __shfl_xor(sq, 1);
  sq += __shfl_xor(sq, 2);
  if ((lane & 3) == 0) dn_s[arow] = sq;
  __syncthreads();

  const float sg  = sigma[0];
  const float inv = 0.5f / (sg * sg);
  float dn[2][4];
  bool ok[2][4];
#pragma unroll
  for (int i = 0; i < 2; ++i)
#pragma unroll
    for (int r = 0; r < 4; ++r) {
      int rl = wr * 32 + i * 16 + kg * 4 + r;
      dn[i][r] = dn_s[rl];
      ok[i][r] = (n0 + rl) < NDATA;
    }

  // pass 1: block-local column max
  float pm[8];
#pragma unroll
  for (int c = 0; c < 8; ++c) pm[c] = -1e30f;
#pragma unroll
  for (int i = 0; i < 2; ++i)
#pragma unroll
    for (int r = 0; r < 4; ++r)
#pragma unroll
      for (int c = 0; c < 8; ++c) {
        float v = ok[i][r] ? (2.f * acc[i][c][r] - dn[i][r]) * inv : -1e30f;
        pm[c] = fmaxf(pm[c], v);
      }
#pragma unroll
  for (int c = 0; c < 8; ++c) {
    pm[c] = fmaxf(pm[c], __shfl_xor(pm[c], 16));
    pm[c] = fmaxf(pm[c], __shfl_xor(pm[c], 32));
  }
  if (kg == 0) {
#pragma unroll
    for (int c = 0; c < 8; ++c) m4[wr * 256 + wb * 128 + c * 16 + l15] = pm[c];
  }
  __syncthreads();
  if (tid < 256)
    m_s[tid] = fmaxf(fmaxf(m4[tid], m4[256 + tid]), fmaxf(m4[512 + tid], m4[768 + tid]));
  __syncthreads();

  float mcol[8];
#pragma unroll
  for (int c = 0; c < 8; ++c) mcol[c] = m_s[wb * 128 + c * 16 + l15];

  // pass 2: two 64-n chunks through the trans buffer
  float pl[8] = {};
#pragma unroll
  for (int h = 0; h < 2; ++h) {
    if ((wr >> 1) == h) {
#pragma unroll
      for (int i = 0; i < 2; ++i)
#pragma unroll
        for (int r = 0; r < 4; ++r) {
          const int rl2 = (wr & 1) * 32 + i * 16 + kg * 4 + r;
#pragma unroll
          for (int c = 0; c < 8; ++c) {
            float v = (2.f * acc[i][c][r] - dn[i][r]) * inv;
            float w = ok[i][r] ? __expf(v - mcol[c]) : 0.f;
            pl[c] += w;
            trans[(wb * 128 + c * 16 + l15) * 72 + rl2] = (f16)w;
          }
        }
    }
    __syncthreads();
    {
      const int col = tid >> 1, q = tid & 1;
      const f16* src = trans + col * 72 + q * 32;
      f16* dst = W + (size_t)col * NW + n0 + h * 64 + q * 32;
#pragma unroll
      for (int j = 0; j < 4; ++j)
        *(f16x8*)(dst + j * 8) = *(const f16x8*)(src + j * 8);
    }
    __syncthreads();
  }

#pragma unroll
  for (int c = 0; c < 8; ++c) {
    pl[c] += __shfl_xor(pl[c], 16);
    pl[c] += __shfl_xor(pl[c], 32);
  }
  if (kg == 0) {
#pragma unroll
    for (int c = 0; c < 8; ++c) l4[wr * 256 + wb * 128 + c * 16 + l15] = pl[c];
  }
  __syncthreads();
  if (tid < 256) {
    Mp[blockIdx.x * 256 + tid] = m_s[tid];
    Lp[blockIdx.x * 256 + tid] = l4[tid] + l4[256 + tid] + l4[512 + tid] + l4[768 + tid];
  }
}

// ---------------- K3: combine partials -> M[b], L[b] ----------------
__global__ void k_comb(const float* __restrict__ Mp, const float* __restrict__ Lp,
                       float* __restrict__ M, float* __restrict__ L, int ngrp) {
  __shared__ float ms[4][256], ls[4][256];
  const int tid = threadIdx.x;
  const int q = tid >> 8, b = tid & 255;
  float m = -1e38f, l = 0.f;
  for (int g = q; g < ngrp; g += 4) {
    float m2 = Mp[g * 256 + b], l2 = Lp[g * 256 + b];
    if (m2 > m) { l = l * __expf(m - m2) + l2; m = m2; }
    else        { l += l2 * __expf(m2 - m); }
  }
  ms[q][b] = m; ls[q][b] = l;
  __syncthreads();
  if (q == 0) {
#pragma unroll
    for (int j = 1; j < 4; ++j) {
      float m2 = ms[j][b], l2 = ls[j][b];
      if (m2 > m) { l = l * __expf(m - m2) + l2; m = m2; }
      else        { l += l2 * __expf(m2 - m); }
    }
    M[b] = m; L[b] = l;
  }
}

// ---------------- K4: eps partials = (W*exp(Mp-M)) @ data, split-K over n ----------------
// 512 thr, tile 256b x 64d, K-step 32. Rescale fused into A-fragments.
__global__ __launch_bounds__(512, 4) void k_pv(const float* __restrict__ data,
                                               const f16* __restrict__ W,
                                               const float* __restrict__ Mp,
                                               const float* __restrict__ M,
                                               float* __restrict__ part,
                                               int chn, int per8) {
  __shared__ f16 T[2][64 * 40];   // [d][n(32)+pad]
  const int tid = threadIdx.x;
  const int wid = tid >> 6, lane = tid & 63;
  const int l15 = lane & 15, kg = lane >> 4;
  const int bid = blockIdx.x;
  const int swz = (bid & 7) * per8 + (bid >> 3);   // XCD-chunked (grid % 8 == 0)
  const int chunk = swz / NDT2;
  const int dt = swz % NDT2;
  const int d0 = dt * 64;
  const int nstart = chunk * chn;
  const int kst = chn >> 5;
  const int nl = tid >> 4, dl = (tid & 15) * 4;    // staging: 32 n x 64 d

  f32x4 acc[2][4] = {};
  const int b0 = wid * 32 + l15, b1 = b0 + 16;
  const float Mb0 = M[b0], Mb1 = M[b1];
  const f16* wp0 = W + (size_t)b0 * NW + nstart + kg * 8;
  const f16* wp1 = W + (size_t)b1 * NW + nstart + kg * 8;

  f32x4 gA, gB;
  f16x8 w0c, w1c, w0n, w1n;
  float mpAc, mpBc, mpAn, mpBn;

  auto gload = [&](int ks, f32x4& g) {
    int row = nstart + ks * 32 + nl;
    int rc = row < NDATA ? row : NDATA - 1;        // tail rows have W==0
    g = *(const f32x4*)(data + (size_t)rc * DF + d0 + dl);
  };
  auto wload = [&](int ks, f16x8& w0, f16x8& w1, float& ma, float& mb) {
    w0 = *(const f16x8*)(wp0 + ks * 32);
    w1 = *(const f16x8*)(wp1 + ks * 32);
    int gq = (nstart + ks * 32) >> 7;
    ma = Mp[gq * 256 + b0];
    mb = Mp[gq * 256 + b1];
  };
  auto twrite = [&](int buf, f32x4& g) {
#pragma unroll
    for (int j = 0; j < 4; ++j) {
      int d = dl + j;
      int pn = nl ^ (((d >> 3) & 3) << 3);         // bank swizzle
      T[buf][d * 40 + pn] = (f16)g[j];
    }
  };
  auto compute = [&](int buf, f16x8& w0, f16x8& w1, float ma, float mb) {
    f16 h0 = (f16)__expf(ma - Mb0);
    f16 h1 = (f16)__expf(mb - Mb1);
    f16x8 a0, a1;
#pragma unroll
    for (int j = 0; j < 8; ++j) { a0[j] = w0[j] * h0; a1[j] = w1[j] * h1; }
#pragma unroll
    for (int c = 0; c < 4; ++c) {
      int d = c * 16 + l15;
      int pb = (kg * 8) ^ (((d >> 3) & 3) << 3);
      f16x8 bf = *(const f16x8*)(&T[buf][d * 40 + pb]);
      acc[0][c] = __builtin_amdgcn_mfma_f32_16x16x32_f16(a0, bf, acc[0][c], 0, 0, 0);
      acc[1][c] = __builtin_amdgcn_mfma_f32_16x16x32_f16(a1, bf, acc[1][c], 0, 0, 0);
    }
  };

  gload(0, gA);
  wload(0, w0c, w1c, mpAc, mpBc);
  twrite(0, gA);
  gload(1, gB);
  barrier_lgkm();

  for (int ks = 0; ks < kst; ks += 2) {
    if (ks + 2 < kst) gload(ks + 2, gA);
    if (ks + 1 < kst) wload(ks + 1, w0n, w1n, mpAn, mpBn);
    compute(0, w0c, w1c, mpAc, mpBc);
    if (ks + 1 < kst) twrite(1, gB);
    barrier_lgkm();
    if (ks + 1 < kst) {
      if (ks + 3 < kst) gload(ks + 3, gB);
      if (ks + 2 < kst) wload(ks + 2, w0c, w1c, mpAc, mpBc);
      compute(1, w0n, w1n, mpAn, mpBn);
      if (ks + 2 < kst) twrite(0, gA);
      barrier_lgkm();
    }
  }

  float* pp = part + (size_t)chunk * (BP * DF);
#pragma unroll
  for (int i = 0; i < 2; ++i)
#pragma unroll
    for (int c = 0; c < 4; ++c)
#pragma unroll
      for (int r = 0; r < 4; ++r) {
        int b = wid * 32 + i * 16 + kg * 4 + r;
        int d = d0 + c * 16 + l15;
        pp[(size_t)b * DF + d] = acc[i][c][r];
      }
}

// ---------------- K5: out = (x - (sum partials)/L) / sigma ----------------
__global__ void k_final(const float* __restrict__ x, const float* __restrict__ sigma,
                        const float* __restrict__ part, const float* __restrict__ L,
                        float* __restrict__ out, int nch) {
  int i = blockIdx.x * 256 + threadIdx.x;
  int b = (i * 4) / DF;
  f32x4 s = {};
  for (int c = 0; c < nch; ++c) s += ((const f32x4*)(part + (size_t)c * BP * DF))[i];
  f32x4 xv = ((const f32x4*)x)[i];
  float invL = 1.f / L[b];
  float invsg = 1.f / sigma[0];
  f32x4 r;
#pragma unroll
  for (int j = 0; j < 4; ++j) r[j] = (xv[j] - s[j] * invL) * invsg;
  ((f32x4*)out)[i] = r;
}

extern "C" void kernel_launch(void* const* d_in, const int* in_sizes, int n_in,
                              void* d_out, int out_size, void* d_ws, size_t ws_size,
                              hipStream_t stream) {
  const float* x     = (const float*)d_in[0];
  const float* sigma = (const float*)d_in[1];
  const float* data  = (const float*)d_in[2];
  float* out = (float*)d_out;
  char* ws = (char*)d_ws;

  f16*   W  = (f16*)(ws + OFF_W);
  f16*   xh = (f16*)(ws + OFF_XH);
  float* Mp = (float*)(ws + OFF_MP);
  float* Lp = (float*)(ws + OFF_LP);
  float* M  = (float*)(ws + OFF_M);
  float* L  = (float*)(ws + OFF_L);
  float* P  = (float*)(ws + OFF_P);

  int nch = 24, chn = 2112;                         // 24*2112 = 50688 exactly
  if (ws_size < OFF_P + 24 * SLAB) { nch = 16; chn = 3168; }
  if (ws_size < OFF_P + 16 * SLAB) { nch = 8;  chn = 6336; }
  const int grid_pv = NDT2 * nch;
  const int per8 = grid_pv / 8;

  k_prep_x<<<768, 256, 0, stream>>>(x, xh);
  k_qk<<<NGRPQ, 512, 0, stream>>>(data, xh, sigma, W, Mp, Lp);
  k_comb<<<1, 1024, 0, stream>>>(Mp, Lp, M, L, NGRPQ);
  k_pv<<<grid_pv, 512, 0, stream>>>(data, W, Mp, M, P, chn, per8);
  k_final<<<768, 256, 0, stream>>>(x, sigma, P, L, out, nch);
}